// Round 10
// baseline (203.969 us; speedup 1.0000x reference)
//
#include <hip/hip_runtime.h>
#include <hip/hip_bf16.h>
#include <math.h>

#define B_ 2
#define S_ 2048
#define E_ 1024
#define H_ 16
#define D_ 64
#define M_ (B_*S_)

typedef __attribute__((ext_vector_type(8))) short short8v;
typedef __attribute__((ext_vector_type(4))) float floatx4;

__device__ __forceinline__ short f2bf(float f) {
    union { float f; unsigned u; } x; x.f = f;
    unsigned r = (x.u + 0x7fffu + ((x.u >> 16) & 1u)) >> 16;  // RNE
    return (short)r;
}

__device__ __forceinline__ unsigned pk_bf16(float a, float b) {
    union { float f; unsigned u; } x, y;
    x.f = a; y.f = b;
    return __builtin_amdgcn_perm(y.u + 0x8000u, x.u + 0x8000u, 0x07060302u);
}

__device__ __forceinline__ float fast_exp2(float x) {
#if __has_builtin(__builtin_amdgcn_exp2f)
    return __builtin_amdgcn_exp2f(x);
#else
    return __expf(x * 0.6931471805599453f);
#endif
}

__device__ __forceinline__ void gl2lds16(const void* g, void* l) {
    __builtin_amdgcn_global_load_lds(
        (const __attribute__((address_space(1))) void*)g,
        (__attribute__((address_space(3))) void*)l, 16, 0, 0);
}

// 3-term XOR swizzle for 32-col (64B-row) bf16 LDS tiles: logical (row,
// 16B-chunk cg) -> row*32 + phys*8, phys = cg ^ (row&3) ^ ((row>>2)&3).
// Fragment reads then hit each bank at most 2-way (free, m136).
__device__ __forceinline__ int swz32(int row, int cg) {
    return row*32 + (((cg ^ (row & 3) ^ ((row >> 2) & 3)) & 3) << 3);
}

// ---------------------------------------------------------------------------
// Prep: z<4 -> W [k][n] fp32 -> Wt [n][k] bf16 (32x32 transpose);
//       z==4 -> x fp32 -> bf16 flat (1024 blocks x 4096 elems).
// ---------------------------------------------------------------------------
__global__ __launch_bounds__(256) void prep(
    const float* __restrict__ x, short* __restrict__ xb,
    const float* __restrict__ W0, const float* __restrict__ W1,
    const float* __restrict__ W2, const float* __restrict__ W3,
    short* __restrict__ T0, short* __restrict__ T1,
    short* __restrict__ T2, short* __restrict__ T3)
{
    const int z = blockIdx.z;
    if (z == 4) {
        const size_t i = ((size_t)(blockIdx.y*32 + blockIdx.x))*4096 + threadIdx.x*16;
        #pragma unroll
        for (int j=0;j<2;j++) {
            float4 a = *(const float4*)(x + i + j*8);
            float4 b = *(const float4*)(x + i + j*8 + 4);
            int4 p = { (int)pk_bf16(a.x,a.y), (int)pk_bf16(a.z,a.w),
                       (int)pk_bf16(b.x,b.y), (int)pk_bf16(b.z,b.w) };
            *(int4*)(xb + i + j*8) = p;
        }
        return;
    }
    const float* W = (z==0)?W0:(z==1)?W1:(z==2)?W2:W3;
    short*       T = (z==0)?T0:(z==1)?T1:(z==2)?T2:T3;
    __shared__ float tile[32][33];
    const int k0 = blockIdx.y*32, n0 = blockIdx.x*32;
    const int r = threadIdx.x >> 5, c = threadIdx.x & 31;
    #pragma unroll
    for (int i=0;i<4;i++)
        tile[r+8*i][c] = W[(size_t)(k0+r+8*i)*E_ + n0 + c];
    __syncthreads();
    #pragma unroll
    for (int i=0;i<4;i++)
        T[(size_t)(n0+r+8*i)*E_ + k0 + c] = f2bf(tile[c][r+8*i]);
}

// ---------------------------------------------------------------------------
// Fused QKV GEMM, PIPELINED staging (R10): 128x128 tile, BK=32, LDS dbuf.
// Loop: stage(k+1 -> buf p^1) right after the barrier; compute buf p; barrier.
// The vmcnt(0)-before-barrier now drains loads that had a full compute phase
// in flight (R9's stage->barrier->compute exposed the whole L2 service time).
// Grid 768: m = lin&31 (XCD locality), nf = lin>>5 over fused 3072 cols.
// ---------------------------------------------------------------------------
__global__ __launch_bounds__(256) void qkv_gemm(
    const short* __restrict__ xb, const short* __restrict__ Wt,
    const float* __restrict__ bq, const float* __restrict__ bk, const float* __restrict__ bv,
    short* __restrict__ Qo, short* __restrict__ Ko, short* __restrict__ Vo)
{
    __shared__ __align__(16) short As[2][128*32];
    __shared__ __align__(16) short Bs[2][128*32];

    const int t = threadIdx.x;
    const int wave = t >> 6, lane = t & 63;
    const int quad = lane >> 4, l15 = lane & 15;
    const int lin = blockIdx.x;
    const int m0  = (lin & 31) * 128;
    const int nf0 = (lin >> 5) * 128;
    const int z   = nf0 >> 10;
    const float* bb = (z==0) ? bq : (z==1) ? bk : bv;
    short* out      = (z==0) ? Qo : (z==1) ? Ko : Vo;
    const float sc  = (z==0) ? 0.18033688011112042f : 1.0f;

    const int mq = (wave & 1)*64, nq = (wave >> 1)*64;
    const int srow = lane >> 2;                                 // row in 16-row slab
    const int scg  = ((lane&3) ^ ((lane>>2)&3) ^ ((lane>>4)&3)) * 8;  // swizzled global col

    floatx4 acc[4][4];
    #pragma unroll
    for (int i=0;i<4;i++)
        #pragma unroll
        for (int j=0;j<4;j++) acc[i][j] = (floatx4){0.f,0.f,0.f,0.f};

    auto stage = [&](int kt, int p) {
        const int k0 = kt << 5;
        #pragma unroll
        for (int j=0;j<2;j++) {
            const int rb = wave*16 + j*64;
            gl2lds16(xb + (size_t)(m0 +rb+srow)*E_ + k0 + scg, &As[p][rb*32]);
            gl2lds16(Wt + (size_t)(nf0+rb+srow)*E_ + k0 + scg, &Bs[p][rb*32]);
        }
    };

    stage(0, 0);
    __syncthreads();
    for (int k = 0; k < 32; k++) {
        const int p = k & 1;
        if (k + 1 < 32) stage(k + 1, p ^ 1);
        short8v a[4], b[4];
        #pragma unroll
        for (int mt=0;mt<4;mt++) a[mt] = *(const short8v*)&As[p][swz32(mq+mt*16+l15, quad)];
        #pragma unroll
        for (int nt=0;nt<4;nt++) b[nt] = *(const short8v*)&Bs[p][swz32(nq+nt*16+l15, quad)];
        #pragma unroll
        for (int mt=0;mt<4;mt++)
            #pragma unroll
            for (int nt=0;nt<4;nt++)
                acc[mt][nt] = __builtin_amdgcn_mfma_f32_16x16x32_bf16(a[mt], b[nt], acc[mt][nt], 0,0,0);
        __syncthreads();
    }

    #pragma unroll
    for (int nt=0;nt<4;nt++) {
        const int nw = (nf0 & 1023) + nq + nt*16 + l15;
        const float bias = bb[nw];
        const int h = nw >> 6, d = nw & 63;
        #pragma unroll
        for (int mt=0;mt<4;mt++) {
            #pragma unroll
            for (int r=0;r<4;r++) {
                const int m = m0 + mq + mt*16 + quad*4 + r;
                const int b2 = m >> 11, s = m & (S_-1);
                const int bh = (b2<<4) + h;
                const float v = (acc[mt][nt][r] + bias) * sc;
                if (z == 0) {
                    out[((size_t)bh*S_ + s)*D_ + d] = f2bf(v);
                } else if (z == 1) {
                    const int ts = s >> 6, kk = s & 63;
                    const int c = kk*8 + ((d>>3) ^ ((kk>>2)&7));
                    out[((size_t)bh*32 + ts)*4096 + c*8 + (d&7)] = f2bf(v);
                } else {
                    const int ts = s >> 6, sk = s & 63;
                    const int c = d*8 + ((sk>>3) ^ (d&7));
                    out[((size_t)bh*32 + ts)*4096 + c*8 + (sk&7)] = f2bf(v);
                }
            }
        }
    }
}

// ---------------------------------------------------------------------------
// Causal flash attention, LDS-staged K/V (unchanged from R8/R9).
// ---------------------------------------------------------------------------
__global__ __launch_bounds__(256, 1) void attn_kernel(
    const short* __restrict__ Q, const short* __restrict__ K, const short* __restrict__ V,
    short* __restrict__ AO)
{
    const int bh = blockIdx.x;
    const int qb = (gridDim.y - 1 - blockIdx.y) * 128;
    const int t = threadIdx.x;
    const int wave = t >> 6, lane = t & 63;
    const int quad = lane >> 4, l15 = lane & 15;

    const short* Qp = Q + (size_t)bh * (S_*D_);
    const short* Kp = K + (size_t)bh * (S_*D_);
    const short* Vp = V + (size_t)bh * (S_*D_);

    __shared__ __align__(16) short KVs[2][8192];
    __shared__ __align__(16) short Psl[2][4][2][16*72];

    const int qA = qb + wave*16;
    const int qB = qb + 64 + wave*16;
    const short* qa = Qp + (size_t)(qA + l15)*D_ + quad*8;
    const short8v qA0 = *(const short8v*)qa, qA1 = *(const short8v*)(qa + 32);
    const short* qbp = Qp + (size_t)(qB + l15)*D_ + quad*8;
    const short8v qB0 = *(const short8v*)qbp, qB1 = *(const short8v*)(qbp + 32);

    const int qrbA = qA + quad*4;
    const int qrbB = qB + quad*4;

    floatx4 oA[4], oB[4];
    #pragma unroll
    for (int i=0;i<4;i++) { oA[i] = (floatx4){0,0,0,0}; oB[i] = (floatx4){0,0,0,0}; }
    float tsA[4] = {0,0,0,0}, tsB[4] = {0,0,0,0};

    const int L = (qb >> 6) + 2;
    const int swz = l15 & 7;

    auto stage = [&](int kt, int p) {
        const short* src = ((wave < 2) ? Kp : Vp) + (size_t)kt*4096 + (wave&1)*2048 + lane*8;
        short* dst = &KVs[p][((wave < 2) ? 0 : 4096) + (wave&1)*2048];
        #pragma unroll
        for (int c=0;c<4;c++)
            gl2lds16(src + c*512, dst + c*512);
    };
    auto qk2 = [&](const short* KL, floatx4 (&sA)[4], floatx4 (&sB)[4]) {
        #pragma unroll
        for (int h=0; h<4; h++) {
            const int rowc = (4*l15 + h)*8;
            short8v b0 = *(const short8v*)(KL + (rowc + (quad       ^ swz))*8);
            short8v b1 = *(const short8v*)(KL + (rowc + ((4 + quad) ^ swz))*8);
            sA[h] = (floatx4){0.f,0.f,0.f,0.f};
            sA[h] = __builtin_amdgcn_mfma_f32_16x16x32_bf16(qA0, b0, sA[h], 0,0,0);
            sA[h] = __builtin_amdgcn_mfma_f32_16x16x32_bf16(qA1, b1, sA[h], 0,0,0);
            sB[h] = (floatx4){0.f,0.f,0.f,0.f};
            sB[h] = __builtin_amdgcn_mfma_f32_16x16x32_bf16(qB0, b0, sB[h], 0,0,0);
            sB[h] = __builtin_amdgcn_mfma_f32_16x16x32_bf16(qB1, b1, sB[h], 0,0,0);
        }
    };
    auto soft_u = [&](floatx4 (&s)[4], float* ts, short* pw, int qrb, int k0) {
        const int kk = k0 + 4*l15;
        #pragma unroll
        for (int r=0; r<4; r++) {
            const int qr = qrb + r;
            float p[4];
            #pragma unroll
            for (int h=0; h<4; h++) {
                const float e = fast_exp2(s[h][r]);
                p[h] = (kk + h > qr) ? 0.f : e;
            }
            ts[r] += (p[0] + p[1]) + (p[2] + p[3]);
            int2 pkv = { (int)pk_bf16(p[0], p[1]), (int)pk_bf16(p[2], p[3]) };
            *(int2*)(pw + (quad*4 + r)*72 + l15*4) = pkv;
        }
    };
    short8v vr[4][2];
    auto loadv = [&](const short* VL) {
        #pragma unroll
        for (int dt=0; dt<4; dt++) {
            const int rowc = (dt*16 + l15)*8;
            vr[dt][0] = *(const short8v*)(VL + (rowc + (quad       ^ swz))*8);
            vr[dt][1] = *(const short8v*)(VL + (rowc + ((4 + quad) ^ swz))*8);
        }
    };
    auto pv = [&](const short* pw, floatx4 (&o)[4]) {
        const short8v pf0 = *(const short8v*)(pw + l15*72 + quad*8);
        const short8v pf1 = *(const short8v*)(pw + l15*72 + 32 + quad*8);
        #pragma unroll
        for (int dt=0; dt<4; dt++) {
            o[dt] = __builtin_amdgcn_mfma_f32_16x16x32_bf16(pf0, vr[dt][0], o[dt], 0,0,0);
            o[dt] = __builtin_amdgcn_mfma_f32_16x16x32_bf16(pf1, vr[dt][1], o[dt], 0,0,0);
        }
    };

    stage(0, 0);
    __syncthreads();
    stage(1, 1);
    {
        floatx4 sA[4], sB[4];
        qk2(&KVs[0][0], sA, sB);
        loadv(&KVs[0][4096]);
        soft_u(sA, tsA, &Psl[0][wave][0][0], qrbA, 0);
        soft_u(sB, tsB, &Psl[0][wave][1][0], qrbB, 0);
    }

    for (int kt = 1; kt < L; kt++) {
        const int p = kt & 1;
        __syncthreads();
        if (kt + 1 < L) stage(kt + 1, p ^ 1);
        floatx4 sA[4], sB[4];
        qk2(&KVs[p][0], sA, sB);
        pv(&Psl[p^1][wave][0][0], oA);
        pv(&Psl[p^1][wave][1][0], oB);
        loadv(&KVs[p][4096]);
        const int k0 = kt << 6;
        soft_u(sA, tsA, &Psl[p][wave][0][0], qrbA, k0);
        soft_u(sB, tsB, &Psl[p][wave][1][0], qrbB, k0);
    }

    pv(&Psl[1][wave][0][0], oA);
    pv(&Psl[1][wave][1][0], oB);

    float lA[4], lB[4];
    #pragma unroll
    for (int r=0; r<4; r++) {
        float a = tsA[r], b = tsB[r];
        #pragma unroll
        for (int off=1; off<16; off<<=1) {
            a += __shfl_xor(a, off);
            b += __shfl_xor(b, off);
        }
        lA[r] = a; lB[r] = b;
    }

    const int b = bh >> 4, h = bh & 15;
    #pragma unroll
    for (int dt=0; dt<4; dt++) {
        #pragma unroll
        for (int r=0; r<4; r++) {
            const int d = dt*16 + l15;
            const int sA_ = qA + quad*4 + r;
            const int sB_ = qB + quad*4 + r;
            AO[((size_t)(b*S_ + sA_)*H_ + h)*D_ + d] = f2bf(oA[dt][r] / lA[r]);
            AO[((size_t)(b*S_ + sB_)*H_ + h)*D_ + d] = f2bf(oB[dt][r] / lB[r]);
        }
    }
}

// ---------------------------------------------------------------------------
// Output GEMM, PIPELINED (R10): 128x128 tile, BK=32, LDS dbuf, grid 256.
// ---------------------------------------------------------------------------
__global__ __launch_bounds__(256) void out_gemm(
    const short* __restrict__ A, const short* __restrict__ Wto,
    const float* __restrict__ bo, float* __restrict__ out)
{
    __shared__ __align__(16) short As[2][128*32];
    __shared__ __align__(16) short Bs[2][128*32];

    const int t = threadIdx.x;
    const int wave = t >> 6, lane = t & 63;
    const int quad = lane >> 4, l15 = lane & 15;
    const int lin = blockIdx.x;
    const int m0 = (lin & 31) * 128;
    const int n0 = (lin >> 5) * 128;
    const int mq = (wave & 1)*64, nq = (wave >> 1)*64;
    const int srow = lane >> 2;
    const int scg  = ((lane&3) ^ ((lane>>2)&3) ^ ((lane>>4)&3)) * 8;

    floatx4 acc[4][4];
    #pragma unroll
    for (int i=0;i<4;i++)
        #pragma unroll
        for (int j=0;j<4;j++) acc[i][j] = (floatx4){0.f,0.f,0.f,0.f};

    auto stage = [&](int kt, int p) {
        const int k0 = kt << 5;
        #pragma unroll
        for (int j=0;j<2;j++) {
            const int rb = wave*16 + j*64;
            gl2lds16(A   + (size_t)(m0+rb+srow)*E_ + k0 + scg, &As[p][rb*32]);
            gl2lds16(Wto + (size_t)(n0+rb+srow)*E_ + k0 + scg, &Bs[p][rb*32]);
        }
    };

    stage(0, 0);
    __syncthreads();
    for (int k = 0; k < 32; k++) {
        const int p = k & 1;
        if (k + 1 < 32) stage(k + 1, p ^ 1);
        short8v a[4], b[4];
        #pragma unroll
        for (int mt=0;mt<4;mt++) a[mt] = *(const short8v*)&As[p][swz32(mq+mt*16+l15, quad)];
        #pragma unroll
        for (int nt=0;nt<4;nt++) b[nt] = *(const short8v*)&Bs[p][swz32(nq+nt*16+l15, quad)];
        #pragma unroll
        for (int mt=0;mt<4;mt++)
            #pragma unroll
            for (int nt=0;nt<4;nt++)
                acc[mt][nt] = __builtin_amdgcn_mfma_f32_16x16x32_bf16(a[mt], b[nt], acc[mt][nt], 0,0,0);
        __syncthreads();
    }

    #pragma unroll
    for (int nt=0;nt<4;nt++) {
        const int n = n0 + nq + nt*16 + l15;
        const float bias = bo[n];
        #pragma unroll
        for (int mt=0;mt<4;mt++) {
            #pragma unroll
            for (int r=0;r<4;r++) {
                const int m = m0 + mq + mt*16 + quad*4 + r;
                out[(size_t)m*E_ + n] = acc[mt][nt][r] + bias;
            }
        }
    }
}

extern "C" void kernel_launch(void* const* d_in, const int* in_sizes, int n_in,
                              void* d_out, int out_size, void* d_ws, size_t ws_size,
                              hipStream_t stream)
{
    const float* x  = (const float*)d_in[0];
    const float* Wq = (const float*)d_in[1];
    const float* bq = (const float*)d_in[2];
    const float* Wk = (const float*)d_in[3];
    const float* bk = (const float*)d_in[4];
    const float* Wv = (const float*)d_in[5];
    const float* bv = (const float*)d_in[6];
    const float* Wo = (const float*)d_in[7];
    const float* bo = (const float*)d_in[8];

    short* xb  = (short*)d_ws;                   // bf16 [4096,1024]
    short* Tq  = xb  + (size_t)M_ * E_;          // bf16 Wq^T [n][k]; Tq|Tk|Tv fused
    short* Tk  = Tq  + (size_t)E_ * E_;
    short* Tv  = Tk  + (size_t)E_ * E_;
    short* To  = Tv  + (size_t)E_ * E_;
    short* Qw  = To  + (size_t)E_ * E_;          // bf16 [B,H,S,D] (exp2-scaled)
    short* Kw  = Qw  + (size_t)M_ * E_;          // bf16 tiled-swizzled K
    short* Vw  = Kw  + (size_t)M_ * E_;          // bf16 tiled-swizzled V
    short* AOw = Vw  + (size_t)M_ * E_;          // bf16 [B,S,H,D]

    dim3 blk(256);
    prep<<<dim3(32, 32, 5), blk, 0, stream>>>(x, xb, Wq, Wk, Wv, Wo, Tq, Tk, Tv, To);
    qkv_gemm<<<dim3(768), blk, 0, stream>>>(xb, Tq, bq, bk, bv, Qw, Kw, Vw);
    attn_kernel<<<dim3(B_*H_, S_/128), blk, 0, stream>>>(Qw, Kw, Vw, AOw);
    out_gemm<<<dim3(256), blk, 0, stream>>>(AOw, To, bo, (float*)d_out);
}